// Round 1
// baseline (561.930 us; speedup 1.0000x reference)
//
#include <hip/hip_runtime.h>
#include <hip/hip_bf16.h>
#include <math.h>

// Shapes (fixed by the problem):
//   x      (4, 65536, 256) f32
//   style  (4, 512) f32
//   weight (1, 256, 256) f32  [c][o]
//   mod_w  (256, 512) f32
//   mod_b  (256,) f32
//   out    (4, 65536, 256) f32
#define IN_C   256
#define OUT_C  256
#define SDIM   512
#define NROWS  65536

constexpr float EPS       = 1e-8f;
constexpr float SCALE     = 0.0625f;               // 1/sqrt(256)
constexpr float MOD_SCALE = 0.04419417382415922f;  // 1/sqrt(512)

typedef __bf16 bf16x8 __attribute__((ext_vector_type(8)));
typedef float  f32x4  __attribute__((ext_vector_type(4)));

// ---------------------------------------------------------------------------
// Kernel 1: per-batch modulated + demodulated weight, stored TRANSPOSED
// wt[b][o][c] (bf16) so the GEMM's B-fragment (8 consecutive k at fixed col o)
// is one contiguous 16B load.
// ---------------------------------------------------------------------------
__global__ __launch_bounds__(256) void modw_kernel(
    const float* __restrict__ style,
    const float* __restrict__ weight,
    const float* __restrict__ mod_w,
    const float* __restrict__ mod_b,
    __bf16* __restrict__ wt)
{
    const int b = blockIdx.x;
    const int t = threadIdx.x;

    __shared__ float s_lds[IN_C];
    __shared__ float demod_lds[OUT_C];

    // Phase A: s[c] = dot(style[b,:], mod_w[c,:]) * MOD_SCALE + mod_b[c] + 1
    {
        const float* st = style + b * SDIM;
        const float* mw = mod_w + t * SDIM;
        float dot = 0.f;
        #pragma unroll 4
        for (int j = 0; j < SDIM; j += 4) {
            float4 a = *(const float4*)(st + j);
            float4 w = *(const float4*)(mw + j);
            dot += a.x * w.x + a.y * w.y + a.z * w.z + a.w * w.w;
        }
        s_lds[t] = dot * MOD_SCALE + mod_b[t] + 1.0f;
    }
    __syncthreads();

    // Phase B: demod[o] = 1/sqrt(sum_c (SCALE*weight[c][o]*s[c])^2 + EPS)
    {
        float sum = 0.f;
        #pragma unroll 4
        for (int c = 0; c < IN_C; ++c) {
            float wv = SCALE * weight[c * OUT_C + t] * s_lds[c];
            sum += wv * wv;
        }
        demod_lds[t] = 1.0f / sqrtf(sum + EPS);
    }
    __syncthreads();

    // Phase C: wt[b][o][c] = SCALE*weight[c][o]*s[c]*demod[o].  thread owns c=t
    // (reads contiguous per-lane; 2B stores coalesced across lanes)
    {
        const float srow = SCALE * s_lds[t];
        __bf16* w_out = wt + b * (IN_C * OUT_C);
        const float* wrow = weight + t * OUT_C;
        #pragma unroll 4
        for (int o = 0; o < OUT_C; o += 4) {
            float4 wv = *(const float4*)(wrow + o);
            w_out[(o + 0) * IN_C + t] = (__bf16)(wv.x * srow * demod_lds[o + 0]);
            w_out[(o + 1) * IN_C + t] = (__bf16)(wv.y * srow * demod_lds[o + 1]);
            w_out[(o + 2) * IN_C + t] = (__bf16)(wv.z * srow * demod_lds[o + 2]);
            w_out[(o + 3) * IN_C + t] = (__bf16)(wv.w * srow * demod_lds[o + 3]);
        }
    }
}

// ---------------------------------------------------------------------------
// Kernel 2: out[b] = x[b] (65536x256, f32->bf16) @ wt[b]^T  via MFMA.
// 256 threads = 4 waves; wave w owns N-quarter [w*64, w*64+64).
// All B fragments held in registers (32 x bf16x8 = 128 VGPR), loaded once.
// Each block loops 8 M-tiles of 32 rows. No LDS, no barriers.
// ---------------------------------------------------------------------------
__global__ __launch_bounds__(256, 2) void gemm_kernel(
    const float* __restrict__ x,
    const __bf16* __restrict__ wt,
    float* __restrict__ out)
{
    const int lane = threadIdx.x & 63;
    const int wid  = threadIdx.x >> 6;   // n-quarter
    const int b    = blockIdx.x >> 8;    // 256 blocks per batch
    const int tgrp = blockIdx.x & 255;

    const int l15 = lane & 15;
    const int kb  = (lane >> 4) * 8;     // k-chunk base within 32-wide k-step

    // Load B fragments once: lane l -> col (wid*64 + nt*16 + l15), k = ks*32+kb..+7
    bf16x8 bfrag[4][8];
    {
        const __bf16* wb = wt + b * (IN_C * OUT_C) + (wid * 64 + l15) * IN_C + kb;
        #pragma unroll
        for (int nt = 0; nt < 4; ++nt)
            #pragma unroll
            for (int ks = 0; ks < 8; ++ks)
                bfrag[nt][ks] = *(const bf16x8*)(wb + nt * 16 * IN_C + ks * 32);
    }

    const float* xb = x   + (size_t)b * NROWS * IN_C;
    float*       ob = out + (size_t)b * NROWS * OUT_C;

    for (int it = 0; it < 8; ++it) {
        const int m0 = (tgrp + (it << 8)) << 5;   // tile index * 32 rows

        f32x4 acc[2][4] = {};

        #pragma unroll
        for (int ms = 0; ms < 2; ++ms) {
            const float* xr = xb + (size_t)(m0 + ms * 16 + l15) * IN_C + kb;
            #pragma unroll
            for (int ks = 0; ks < 8; ++ks) {
                float4 f0 = *(const float4*)(xr + ks * 32);
                float4 f1 = *(const float4*)(xr + ks * 32 + 4);
                bf16x8 a;
                a[0] = (__bf16)f0.x; a[1] = (__bf16)f0.y;
                a[2] = (__bf16)f0.z; a[3] = (__bf16)f0.w;
                a[4] = (__bf16)f1.x; a[5] = (__bf16)f1.y;
                a[6] = (__bf16)f1.z; a[7] = (__bf16)f1.w;
                #pragma unroll
                for (int nt = 0; nt < 4; ++nt)
                    acc[ms][nt] = __builtin_amdgcn_mfma_f32_16x16x32_bf16(
                        a, bfrag[nt][ks], acc[ms][nt], 0, 0, 0);
            }
        }

        // Store: D lane mapping col = l15, row = (lane>>4)*4 + r
        const int r0 = (lane >> 4) * 4;
        #pragma unroll
        for (int ms = 0; ms < 2; ++ms) {
            #pragma unroll
            for (int nt = 0; nt < 4; ++nt) {
                float* orow = ob + (size_t)(m0 + ms * 16 + r0) * OUT_C
                                 + wid * 64 + nt * 16 + l15;
                #pragma unroll
                for (int r = 0; r < 4; ++r)
                    orow[(size_t)r * OUT_C] = acc[ms][nt][r];
            }
        }
    }
}

extern "C" void kernel_launch(void* const* d_in, const int* in_sizes, int n_in,
                              void* d_out, int out_size, void* d_ws, size_t ws_size,
                              hipStream_t stream) {
    const float* x      = (const float*)d_in[0];
    const float* style  = (const float*)d_in[1];
    const float* weight = (const float*)d_in[2];
    const float* mod_w  = (const float*)d_in[3];
    const float* mod_b  = (const float*)d_in[4];
    float* out = (float*)d_out;
    __bf16* wt = (__bf16*)d_ws;   // 4*256*256 bf16 = 512 KB

    modw_kernel<<<4, 256, 0, stream>>>(style, weight, mod_w, mod_b, wt);
    gemm_kernel<<<1024, 256, 0, stream>>>(x, wt, out);
}